// Round 15
// baseline (126.685 us; speedup 1.0000x reference)
//
#include <hip/hip_runtime.h>

constexpr int D  = 128;   // feature dim (= H*F)
constexpr int NH = 4;     // heads
constexpr int NF = 32;    // features per head

typedef __attribute__((ext_vector_type(8))) short bfrag;   // 8 bf16 = 4 VGPR
typedef __attribute__((ext_vector_type(4))) float ffrag;   // 4 f32 acc

// bf16 RNE helpers
__device__ __forceinline__ unsigned short bf16h(float x) {
    unsigned u = __float_as_uint(x);
    u += 0x7fffu + ((u >> 16) & 1u);
    return (unsigned short)(u >> 16);
}
__device__ __forceinline__ float bf16tof(unsigned short h) {
    return __uint_as_float(((unsigned)h) << 16);
}

// async global->LDS, 16B/lane: LDS dst = wave-uniform base + lane*16.
__device__ __forceinline__ void gload_lds16(const unsigned short* g, unsigned short* l)
{
    __builtin_amdgcn_global_load_lds(
        (const __attribute__((address_space(1))) void*)g,
        (__attribute__((address_space(3))) void*)l, 16, 0, 0);
}

// ---- launch 1: wsplit (blocks 0..15) + zero counters (blocks 16..) ----
// wsplit output: 1KB chunks indexed ((L*2+plane)*32 + ct*4 + ks); chunk[lane][i]
// = plane(W[ks*32 + (lane>>4)*8 + i][ct*16 + (lane&15)]).
__global__ __launch_bounds__(256) void prep_kernel(
    const float* __restrict__ W1, const float* __restrict__ W2,
    unsigned short* __restrict__ wt, int* __restrict__ cnt, int nz)
{
    if (blockIdx.x < 16) {
        const int L  = blockIdx.x >> 3;
        const int ct = blockIdx.x & 7;
        const float* W = L ? W2 : W1;
        const int ks   = threadIdx.x >> 6;
        const int lane = threadIdx.x & 63;
        const int lg = lane >> 4, lc = lane & 15;
        unsigned short* Hp = wt + ((size_t)(L * 2 + 0) * 32 + ct * 4 + ks) * 512 + lane * 8;
        unsigned short* Lp = wt + ((size_t)(L * 2 + 1) * 32 + ct * 4 + ks) * 512 + lane * 8;
        #pragma unroll
        for (int i = 0; i < 8; ++i) {
            const int k = ks * 32 + lg * 8 + i;
            const int c = ct * 16 + lc;
            const float v = W[(size_t)k * 128 + c];
            const unsigned short hh = bf16h(v);
            Hp[i] = hh;
            Lp[i] = bf16h(v - bf16tof(hh));
        }
    } else {
        const int i4 = ((blockIdx.x - 16) * 256 + threadIdx.x) * 4;
        if (i4 + 3 < nz) {
            *(int4*)&cnt[i4] = {0, 0, 0, 0};
        } else if (i4 < nz) {
            for (int i = i4; i < nz; ++i) cnt[i] = 0;
        }
    }
}

// ---- launch 2: k-half LDS-staged MFMA MLP (32KB, all blocks resident) ----
// R11 proved LDS-fed B has the best per-block time (~30us) but its 64KB buffer
// halved residency (2 rounds -> 61us). R5 proved full residency at 44.7us with
// slower global-B. Combine: stage HALF a layer's K-range (32 chunks = 32KB)
// per barrier phase; accumulator persists across the two k-half phases. h1
// transpose scratch overlays the same 32KB. PW=128 (EXACTLY 128 u32/row —
// R14's PW=124 overlapped rows and failed correctness; 4w*16*128*4 = 32768B).
__global__ __launch_bounds__(256, 4) void mlp_hist_kernel(
    const float* __restrict__ X,
    const unsigned short* __restrict__ WF,
    const float* __restrict__ b1, const float* __restrict__ g1, const float* __restrict__ be1,
    const float* __restrict__ b2, const float* __restrict__ g2, const float* __restrict__ be2,
    unsigned short* __restrict__ Q, int N,
    const int* __restrict__ recv, int* __restrict__ cnt, int E, int mlpBlocks)
{
    __shared__ unsigned short Wlds[16384];     // 32KB: k-half staging / h1 scratch

    if (blockIdx.x >= mlpBlocks) {
        // ---- histogram role ----
        const int tid0   = (blockIdx.x - mlpBlocks) * 256 + threadIdx.x;
        const int stride = (gridDim.x - mlpBlocks) * 256;
        for (int i = tid0; i < E; i += stride) atomicAdd(&cnt[recv[i]], 1);
        return;
    }

    constexpr int PW = 128;                    // u32 pitch: 128/row, 4w*16*128*4 = 32768B
    const int tid  = threadIdx.x;
    const int lane = tid & 63;
    const int wave = tid >> 6;
    const int lc   = lane & 15;
    const int lg   = lane >> 4;
    const int n0w  = blockIdx.x * 64 + wave * 16;   // may exceed N; no early return (barriers)

    bfrag ah[4], al[4];
    ffrag acc[8];

    // ---- A-frags layer 1: from global X (clamped rows), split in-reg ----
    {
        const int row = n0w + lc;
        const int rowx = (row < N) ? row : (N - 1);
        const float* xr = X + (size_t)rowx * 128 + lg * 8;
        #pragma unroll
        for (int ks = 0; ks < 4; ++ks) {
            const float4 a = *(const float4*)&xr[ks * 32];
            const float4 b = *(const float4*)&xr[ks * 32 + 4];
            const float f[8] = {a.x, a.y, a.z, a.w, b.x, b.y, b.z, b.w};
            #pragma unroll
            for (int i = 0; i < 8; ++i) {
                const unsigned short hh = bf16h(f[i]);
                ah[ks][i] = (short)hh;
                al[ks][i] = (short)bf16h(f[i] - bf16tof(hh));
            }
        }
    }

    // ---- hoist LN params ----
    float b1v[8], g1v[8], t1v[8], b2v[8], g2v[8], t2v[8];
    #pragma unroll
    for (int ct = 0; ct < 8; ++ct) {
        const int col = ct * 16 + lc;
        b1v[ct] = b1[col]; g1v[ct] = g1[col]; t1v[ct] = be1[col];
        b2v[ct] = b2[col]; g2v[ct] = g2[col]; t2v[ct] = be2[col];
    }

// stage one k-half (ks in {2h,2h+1}) of a layer: 32 chunks (hi+lo x 8ct x 2ks).
// slot s = p*16 + ct*2 + ksl; wave stages slots wave*8 .. wave*8+7.
#define STAGE_KHALF(hiBase, loBase, h)                                         \
    {                                                                          \
        _Pragma("unroll")                                                      \
        for (int i_ = 0; i_ < 8; ++i_) {                                       \
            const int s_   = wave * 8 + i_;                                    \
            const int p_   = s_ >> 4;                                          \
            const int ct_  = (s_ & 15) >> 1;                                   \
            const int ksl_ = s_ & 1;                                           \
            const int chunk_ = (p_ ? (loBase) : (hiBase)) + ct_ * 4 + 2 * (h) + ksl_; \
            gload_lds16(WF + (size_t)chunk_ * 512 + lane * 8, &Wlds[s_ * 512]);\
        }                                                                      \
    }

// GEMM over one staged k-half: B from LDS; A-frag index = 2h+ksl.
#define GEMM_KHALF(h)                                                          \
    _Pragma("unroll")                                                          \
    for (int ct_ = 0; ct_ < 8; ++ct_) {                                        \
        ffrag a_ = acc[ct_];                                                   \
        _Pragma("unroll")                                                      \
        for (int ksl_ = 0; ksl_ < 2; ++ksl_) {                                 \
            const bfrag bh_ = *(const bfrag*)&Wlds[(ct_ * 2 + ksl_) * 512 + lane * 8];      \
            const bfrag bl_ = *(const bfrag*)&Wlds[(16 + ct_ * 2 + ksl_) * 512 + lane * 8]; \
            const int k_ = 2 * (h) + ksl_;                                     \
            a_ = __builtin_amdgcn_mfma_f32_16x16x32_bf16(ah[k_], bh_, a_, 0, 0, 0); \
            a_ = __builtin_amdgcn_mfma_f32_16x16x32_bf16(ah[k_], bl_, a_, 0, 0, 0); \
            a_ = __builtin_amdgcn_mfma_f32_16x16x32_bf16(al[k_], bh_, a_, 0, 0, 0); \
        }                                                                      \
        acc[ct_] = a_;                                                         \
    }

    // ================= layer 1 =================
    #pragma unroll
    for (int i = 0; i < 8; ++i) acc[i] = (ffrag){0.f, 0.f, 0.f, 0.f};

    STAGE_KHALF(0, 32, 0)
    __syncthreads();                 // k-half 0 resident
    GEMM_KHALF(0)
    __syncthreads();                 // reads done before overwrite
    STAGE_KHALF(0, 32, 1)
    __syncthreads();                 // k-half 1 resident
    GEMM_KHALF(1)
    __syncthreads();                 // reads done before scratch overlay

    // ---- LN1 + ReLU -> packed hi|lo u32 into per-wave scratch (overlay) ----
    unsigned* scr = (unsigned*)Wlds + wave * (16 * PW);
    #pragma unroll
    for (int j = 0; j < 4; ++j) {
        float t[8], s = 0.f, ss = 0.f;
        #pragma unroll
        for (int ct = 0; ct < 8; ++ct) {
            t[ct] = acc[ct][j] + b1v[ct];
            s += t[ct]; ss += t[ct] * t[ct];
        }
        #pragma unroll
        for (int off = 1; off <= 8; off <<= 1) {
            s  += __shfl_xor(s,  off, 16);
            ss += __shfl_xor(ss, off, 16);
        }
        const float mu   = s * (1.f / 128.f);
        const float var  = fmaxf(ss * (1.f / 128.f) - mu * mu, 0.f);
        const float rstd = rsqrtf(var + 1e-6f);
        const int row = lg * 4 + j;
        #pragma unroll
        for (int ct = 0; ct < 8; ++ct) {
            const float o = fmaxf((t[ct] - mu) * rstd * g1v[ct] + t1v[ct], 0.f);
            const unsigned short hh = bf16h(o);
            const unsigned short ll = bf16h(o - bf16tof(hh));
            scr[row * PW + ct * 16 + lc] = (unsigned)hh | ((unsigned)ll << 16);
        }
    }

    // wave-local fence (own-wave scratch region) + sched fence (rule #18)
    asm volatile("s_waitcnt lgkmcnt(0)" ::: "memory");
    __builtin_amdgcn_sched_barrier(0);

    // ---- A-frags layer 2 from scratch (row = lc, k = ks*32+lg*8+i) ----
    #pragma unroll
    for (int ks = 0; ks < 4; ++ks) {
        const uint4 r0 = *(const uint4*)&scr[lc * PW + ks * 32 + lg * 8];
        const uint4 r1 = *(const uint4*)&scr[lc * PW + ks * 32 + lg * 8 + 4];
        const unsigned rr[8] = {r0.x, r0.y, r0.z, r0.w, r1.x, r1.y, r1.z, r1.w};
        #pragma unroll
        for (int i = 0; i < 8; ++i) {
            ah[ks][i] = (short)(rr[i] & 0xffffu);
            al[ks][i] = (short)(rr[i] >> 16);
        }
    }
    __syncthreads();                 // scratch reads done before W2 staging

    // ================= layer 2 =================
    #pragma unroll
    for (int i = 0; i < 8; ++i) acc[i] = (ffrag){0.f, 0.f, 0.f, 0.f};

    STAGE_KHALF(64, 96, 0)
    __syncthreads();
    GEMM_KHALF(0)
    __syncthreads();
    STAGE_KHALF(64, 96, 1)
    __syncthreads();
    GEMM_KHALF(1)

#undef GEMM_KHALF
#undef STAGE_KHALF

    // ---- LN2 + ReLU -> bf16 q (global, guarded) ----
    #pragma unroll
    for (int j = 0; j < 4; ++j) {
        float t[8], s = 0.f, ss = 0.f;
        #pragma unroll
        for (int ct = 0; ct < 8; ++ct) {
            t[ct] = acc[ct][j] + b2v[ct];
            s += t[ct]; ss += t[ct] * t[ct];
        }
        #pragma unroll
        for (int off = 1; off <= 8; off <<= 1) {
            s  += __shfl_xor(s,  off, 16);
            ss += __shfl_xor(ss, off, 16);
        }
        const float mu   = s * (1.f / 128.f);
        const float var  = fmaxf(ss * (1.f / 128.f) - mu * mu, 0.f);
        const float rstd = rsqrtf(var + 1e-6f);
        const int grow = n0w + lg * 4 + j;
        if (grow < N) {
            #pragma unroll
            for (int ct = 0; ct < 8; ++ct) {
                const float o = fmaxf((t[ct] - mu) * rstd * g2v[ct] + t2v[ct], 0.f);
                Q[(size_t)grow * 128 + ct * 16 + lc] = bf16h(o);
            }
        }
    }
}

// ---- CSR build: per-1024-chunk exclusive scan ----
__global__ __launch_bounds__(256) void scan_blocks_kernel(
    const int* __restrict__ cnt, int* __restrict__ rowptr,
    int* __restrict__ bsum, int N)
{
    __shared__ int lds[256];
    const int tid = threadIdx.x;
    const int base = blockIdx.x * 1024 + tid * 4;
    int v0 = (base + 0 < N) ? cnt[base + 0] : 0;
    int v1 = (base + 1 < N) ? cnt[base + 1] : 0;
    int v2 = (base + 2 < N) ? cnt[base + 2] : 0;
    int v3 = (base + 3 < N) ? cnt[base + 3] : 0;
    const int tsum = v0 + v1 + v2 + v3;
    lds[tid] = tsum;
    __syncthreads();
    for (int off = 1; off < 256; off <<= 1) {
        int t = (tid >= off) ? lds[tid - off] : 0;
        __syncthreads();
        lds[tid] += t;
        __syncthreads();
    }
    int run = lds[tid] - tsum;
    if (base + 0 < N) rowptr[base + 0] = run;
    run += v0;
    if (base + 1 < N) rowptr[base + 1] = run;
    run += v1;
    if (base + 2 < N) rowptr[base + 2] = run;
    run += v2;
    if (base + 3 < N) rowptr[base + 3] = run;
    if (tid == 255) bsum[blockIdx.x] = lds[255];
}

// ---- CSR build: scan block sums ----
__global__ __launch_bounds__(256) void scan_top_kernel(int* bsum, int nb)
{
    __shared__ int lds[256];
    const int tid = threadIdx.x;
    int v = (tid < nb) ? bsum[tid] : 0;
    lds[tid] = v;
    __syncthreads();
    for (int off = 1; off < 256; off <<= 1) {
        int t = (tid >= off) ? lds[tid - off] : 0;
        __syncthreads();
        lds[tid] += t;
        __syncthreads();
    }
    if (tid < nb) bsum[tid] = lds[tid] - v;
}

// ---- CSR build: add chunk offsets ----
__global__ __launch_bounds__(256) void scan_add_kernel(
    int* __restrict__ rowptr, int* __restrict__ cursor,
    const int* __restrict__ bsum, int N, int E)
{
    int i = blockIdx.x * blockDim.x + threadIdx.x;
    if (i < N) {
        int v = rowptr[i] + bsum[i >> 10];
        rowptr[i] = v;
        cursor[i] = v;
    }
    if (i == 0) rowptr[N] = E;
}

// ---- CSR build: bucket-fill sorted sender ids ----
__global__ __launch_bounds__(256) void fill_kernel(
    const int* __restrict__ senders, const int* __restrict__ receivers,
    int* __restrict__ cursor, int* __restrict__ ssend, int E)
{
    int e = blockIdx.x * blockDim.x + threadIdx.x;
    if (e < E) {
        int r = receivers[e];
        int pos = atomicAdd(&cursor[r], 1);
        ssend[pos] = senders[e];
    }
}

// ---- fused per-node attention (bf16 q), DUAL-STREAM per half ----
__global__ __launch_bounds__(256) void node_attn_kernel(
    const unsigned short* __restrict__ q, const int* __restrict__ rowptr,
    const int* __restrict__ ssend, float* __restrict__ out, int N)
{
    const int lane = threadIdx.x & 63;
    const int hl   = lane & 31;
    const int half = lane >> 5;
    const int wid  = (blockIdx.x * blockDim.x + threadIdx.x) >> 6;
    const int nw   = (gridDim.x * blockDim.x) >> 6;

    for (int n = wid; n < N; n += nw) {
        const uint2 braw = *(const uint2*)&q[(size_t)n * D + hl * 4];
        const float b0 = __uint_as_float(braw.x << 16);
        const float b1 = __uint_as_float(braw.x & 0xffff0000u);
        const float b2 = __uint_as_float(braw.y << 16);
        const float b3 = __uint_as_float(braw.y & 0xffff0000u);

        const int beg = rowptr[n], end = rowptr[n + 1];

        float mA = -1e30f, lA = 0.f, cA0 = 0.f, cA1 = 0.f, cA2 = 0.f, cA3 = 0.f;
        float mB = -1e30f, lB = 0.f, cB0 = 0.f, cB1 = 0.f, cB2 = 0.f, cB3 = 0.f;

        auto step = [&](uint2 c, float& m, float& l,
                        float& s0r, float& s1r, float& s2r, float& s3r) {
            const float a0 = __uint_as_float(c.x << 16);
            const float a1 = __uint_as_float(c.x & 0xffff0000u);
            const float a2 = __uint_as_float(c.y << 16);
            const float a3 = __uint_as_float(c.y & 0xffff0000u);
            float p = a0 * b0 + a1 * b1 + a2 * b2 + a3 * b3;
            p += __shfl_xor(p, 1);
            p += __shfl_xor(p, 2);
            p += __shfl_xor(p, 4);
            const float logit = p * 0.17677669529663687f;   // 1/sqrt(32)
            const float nm = fmaxf(m, logit);
            const float sc = __expf(m - nm);
            const float u  = __expf(logit - nm);
            l   = l   * sc + u;
            s0r = s0r * sc + u * a0;
            s1r = s1r * sc + u * a1;
            s2r = s2r * sc + u * a2;
            s3r = s3r * sc + u * a3;
            m = nm;
        };

        int jA = beg + half;
        int jB = jA + 2;
        uint2 rA = {0u, 0u}, rB = {0u, 0u};
        if (jA < end) rA = *(const uint2*)&q[(size_t)ssend[jA] * D + hl * 4];
        if (jB < end) rB = *(const uint2*)&q[(size_t)ssend[jB] * D + hl * 4];

        for (; jB < end; jA += 4, jB += 4) {
            const uint2 cA = rA, cB = rB;
            if (jA + 4 < end)
                rA = *(const uint2*)&q[(size_t)ssend[jA + 4] * D + hl * 4];
            if (jB + 4 < end)
                rB = *(const uint2*)&q[(size_t)ssend[jB + 4] * D + hl * 4];
            step(cA, mA, lA, cA0, cA1, cA2, cA3);
            step(cB, mB, lB, cB0, cB1, cB2, cB3);
        }
        if (jA < end)
            step(rA, mA, lA, cA0, cA1, cA2, cA3);

        // merge stream B into A (in-lane flash merge)
        {
            const float nm = fmaxf(mA, mB);
            const float s0 = __expf(mA - nm), s1 = __expf(mB - nm);
            lA  = lA  * s0 + lB  * s1;
            cA0 = cA0 * s0 + cB0 * s1;
            cA1 = cA1 * s0 + cB1 * s1;
            cA2 = cA2 * s0 + cB2 * s1;
            cA3 = cA3 * s0 + cB3 * s1;
            mA = nm;
        }

        // merge the two halves' states (flash-attention merge)
        const float om  = __shfl_xor(mA, 32);
        const float ol  = __shfl_xor(lA, 32);
        const float oc0 = __shfl_xor(cA0, 32);
        const float oc1 = __shfl_xor(cA1, 32);
        const float oc2 = __shfl_xor(cA2, 32);
        const float oc3 = __shfl_xor(cA3, 32);
        const float nm = fmaxf(mA, om);
        const float s0 = __expf(mA - nm), s1 = __expf(om - nm);
        const float lt = lA * s0 + ol * s1;
        const float inv = (lt > 0.f) ? (1.f / lt) : 0.f;
        float r0 = fmaxf((cA0 * s0 + oc0 * s1) * inv, 0.f);
        float r1 = fmaxf((cA1 * s0 + oc1 * s1) * inv, 0.f);
        float r2 = fmaxf((cA2 * s0 + oc2 * s1) * inv, 0.f);
        float r3 = fmaxf((cA3 * s0 + oc3 * s1) * inv, 0.f);

        // head-mean: lanes hl, hl^8, hl^16, hl^24 hold heads 0..3 of same f
        r0 += __shfl_xor(r0, 8);  r0 += __shfl_xor(r0, 16);
        r1 += __shfl_xor(r1, 8);  r1 += __shfl_xor(r1, 16);
        r2 += __shfl_xor(r2, 8);  r2 += __shfl_xor(r2, 16);
        r3 += __shfl_xor(r3, 8);  r3 += __shfl_xor(r3, 16);
        if (lane < 8) {
            float4 o = {0.25f * r0, 0.25f * r1, 0.25f * r2, 0.25f * r3};
            *(float4*)&out[(size_t)n * NF + lane * 4] = o;
        }
    }
}

extern "C" void kernel_launch(void* const* d_in, const int* in_sizes, int n_in,
                              void* d_out, int out_size, void* d_ws, size_t ws_size,
                              hipStream_t stream)
{
    const float* nodes = (const float*)d_in[0];
    const float* W1    = (const float*)d_in[1];
    const float* b1    = (const float*)d_in[2];
    const float* g1    = (const float*)d_in[3];
    const float* be1   = (const float*)d_in[4];
    const float* W2    = (const float*)d_in[5];
    const float* b2    = (const float*)d_in[6];
    const float* g2    = (const float*)d_in[7];
    const float* be2   = (const float*)d_in[8];
    const int* senders   = (const int*)d_in[9];
    const int* receivers = (const int*)d_in[10];

    const int N = in_sizes[0] / D;
    const int E = in_sizes[9];
    float* out = (float*)d_out;

    char* ws = (char*)d_ws;
    unsigned short* qb = (unsigned short*)ws; ws += (size_t)N * D * 2;
    unsigned short* wt = (unsigned short*)ws; ws += 4 * 128 * 128 * 2;
    int* cnt      = (int*)ws;    ws += (size_t)N * 4;
    int* rowptr   = (int*)ws;    ws += (size_t)(N + 2) * 4;
    int* cursor   = (int*)ws;    ws += (size_t)N * 4;
    int* bsum     = (int*)ws;    ws += 256 * 4;
    int* ssend    = (int*)ws;    ws += (size_t)E * 4;

    const int zb = (N + 1023) / 1024;
    const int mlpBlocks = (N + 63) / 64;
    const int nb = (N + 1023) / 1024;

    // 1: weight split + counter zero
    prep_kernel<<<16 + zb, 256, 0, stream>>>(W1, W2, wt, cnt, N);

    // 2: k-half LDS-staged MFMA MLP + edge histogram (tail blocks)
    mlp_hist_kernel<<<mlpBlocks + 128, 256, 0, stream>>>(
        nodes, wt, b1, g1, be1, b2, g2, be2, qb, N,
        receivers, cnt, E, mlpBlocks);

    // 3-5: CSR scan
    scan_blocks_kernel<<<nb, 256, 0, stream>>>(cnt, rowptr, bsum, N);
    scan_top_kernel<<<1, 256, 0, stream>>>(bsum, nb);
    scan_add_kernel<<<(N + 255) / 256, 256, 0, stream>>>(rowptr, cursor, bsum, N, E);

    // 6: bucket-fill receiver-sorted sender list
    fill_kernel<<<(E + 255) / 256, 256, 0, stream>>>(senders, receivers, cursor, ssend, E);

    // 7: dual-stream fused attention + epilogue
    node_attn_kernel<<<(N + 3) / 4, 256, 0, stream>>>(qb, rowptr, ssend, out, N);
}

// Round 16
// 117.216 us; speedup vs baseline: 1.0808x; 1.0808x over previous
//
#include <hip/hip_runtime.h>

constexpr int D  = 128;   // feature dim (= H*F)
constexpr int NH = 4;     // heads
constexpr int NF = 32;    // features per head

typedef __attribute__((ext_vector_type(8))) short bfrag;   // 8 bf16 = 4 VGPR
typedef __attribute__((ext_vector_type(4))) float ffrag;   // 4 f32 acc

// bf16 RNE helpers
__device__ __forceinline__ unsigned short bf16h(float x) {
    unsigned u = __float_as_uint(x);
    u += 0x7fffu + ((u >> 16) & 1u);
    return (unsigned short)(u >> 16);
}
__device__ __forceinline__ float bf16tof(unsigned short h) {
    return __uint_as_float(((unsigned)h) << 16);
}

// ---- launch 1: wsplit (blocks 0..15) + zero counters (blocks 16..) ----
__global__ __launch_bounds__(256) void prep_kernel(
    const float* __restrict__ W1, const float* __restrict__ W2,
    unsigned short* __restrict__ wt, int* __restrict__ cnt, int nz)
{
    if (blockIdx.x < 16) {
        const int L  = blockIdx.x >> 3;
        const int ct = blockIdx.x & 7;
        const float* W = L ? W2 : W1;
        const int ks   = threadIdx.x >> 6;
        const int lane = threadIdx.x & 63;
        const int lg = lane >> 4, lc = lane & 15;
        unsigned short* Hp = wt + ((size_t)(L * 2 + 0) * 32 + ct * 4 + ks) * 512 + lane * 8;
        unsigned short* Lp = wt + ((size_t)(L * 2 + 1) * 32 + ct * 4 + ks) * 512 + lane * 8;
        #pragma unroll
        for (int i = 0; i < 8; ++i) {
            const int k = ks * 32 + lg * 8 + i;
            const int c = ct * 16 + lc;
            const float v = W[(size_t)k * 128 + c];
            const unsigned short hh = bf16h(v);
            Hp[i] = hh;
            Lp[i] = bf16h(v - bf16tof(hh));
        }
    } else {
        const int i4 = ((blockIdx.x - 16) * 256 + threadIdx.x) * 4;
        if (i4 + 3 < nz) {
            *(int4*)&cnt[i4] = {0, 0, 0, 0};
        } else if (i4 < nz) {
            for (int i = i4; i < nz; ++i) cnt[i] = 0;
        }
    }
}

// ---- launch 2: MFMA MLP, 32 rows/wave (2 tiles share B) + histogram tail ----
// R10's exact kernel (best measured total). Each wave owns TWO 16-row
// tiles that share every B-fragment. 1563 waves x 16 B-batches.
__global__ __launch_bounds__(256, 2) void mlp_hist_kernel(
    const float* __restrict__ X,
    const unsigned short* __restrict__ WF,
    const float* __restrict__ b1, const float* __restrict__ g1, const float* __restrict__ be1,
    const float* __restrict__ b2, const float* __restrict__ g2, const float* __restrict__ be2,
    unsigned short* __restrict__ Q, int N,
    const int* __restrict__ recv, int* __restrict__ cnt, int E, int mlpBlocks)
{
    constexpr int PW = 132;                    // u32 pitch (528B, b128-aligned)
    __shared__ unsigned HL[4 * 2 * 16 * PW];   // 67584 B: [wave][tile][row][k]

    if (blockIdx.x >= mlpBlocks) {
        // ---- histogram role (runs as CUs free up) ----
        const int tid0   = (blockIdx.x - mlpBlocks) * 256 + threadIdx.x;
        const int stride = (gridDim.x - mlpBlocks) * 256;
        for (int i = tid0; i < E; i += stride) atomicAdd(&cnt[recv[i]], 1);
        return;
    }

    const int tid  = threadIdx.x;
    const int lane = tid & 63;
    const int wave = tid >> 6;
    const int lc   = lane & 15;
    const int lg   = lane >> 4;
    const int n0w  = (blockIdx.x * 4 + wave) * 32;   // 32 rows per wave
    if (n0w >= N) return;
    unsigned* hl0 = &HL[(wave * 2 + 0) * 16 * PW];
    unsigned* hl1 = &HL[(wave * 2 + 1) * 16 * PW];

    bfrag ah0[4], al0[4], ah1[4], al1[4];

    // ---- A-frags layer 1 for both tiles: from global X, split in-reg ----
    #pragma unroll
    for (int t = 0; t < 2; ++t) {
        const int row = n0w + t * 16 + lc;
        const int rowx = (row < N) ? row : (N - 1);
        const float* xr = X + (size_t)rowx * 128 + lg * 8;
        #pragma unroll
        for (int ks = 0; ks < 4; ++ks) {
            const float4 a = *(const float4*)&xr[ks * 32];
            const float4 b = *(const float4*)&xr[ks * 32 + 4];
            const float f[8] = {a.x, a.y, a.z, a.w, b.x, b.y, b.z, b.w};
            #pragma unroll
            for (int i = 0; i < 8; ++i) {
                const unsigned short hh = bf16h(f[i]);
                const unsigned short ll = bf16h(f[i] - bf16tof(hh));
                if (t == 0) { ah0[ks][i] = (short)hh; al0[ks][i] = (short)ll; }
                else        { ah1[ks][i] = (short)hh; al1[ks][i] = (short)ll; }
            }
        }
    }

    bfrag Bh0[4], Bl0[4], Bh1[4], Bl1[4];      // two B buffers (32 VGPR each)
    ffrag acc0[8], acc1[8];

#define LOADB(BH, BL, hiBase, loBase, ctg)                                     \
    {                                                                          \
        const unsigned short* hp_ = WF + (size_t)((hiBase) + (ctg) * 4) * 512 + lane * 8; \
        const unsigned short* lp_ = WF + (size_t)((loBase) + (ctg) * 4) * 512 + lane * 8; \
        _Pragma("unroll")                                                      \
        for (int ks_ = 0; ks_ < 4; ++ks_) {                                    \
            BH[ks_] = *(const bfrag*)(hp_ + ks_ * 512);                        \
            BL[ks_] = *(const bfrag*)(lp_ + ks_ * 512);                        \
        }                                                                      \
    }

#define COMPB2(BH, BL, d0, d1)                                                 \
    {                                                                          \
        ffrag aH0_ = (ffrag){0.f,0.f,0.f,0.f}, aX0_ = (ffrag){0.f,0.f,0.f,0.f};\
        ffrag aH1_ = (ffrag){0.f,0.f,0.f,0.f}, aX1_ = (ffrag){0.f,0.f,0.f,0.f};\
        _Pragma("unroll")                                                      \
        for (int ks_ = 0; ks_ < 4; ++ks_) {                                    \
            aH0_ = __builtin_amdgcn_mfma_f32_16x16x32_bf16(ah0[ks_], BH[ks_], aH0_, 0, 0, 0); \
            aH1_ = __builtin_amdgcn_mfma_f32_16x16x32_bf16(ah1[ks_], BH[ks_], aH1_, 0, 0, 0); \
            aX0_ = __builtin_amdgcn_mfma_f32_16x16x32_bf16(ah0[ks_], BL[ks_], aX0_, 0, 0, 0); \
            aX1_ = __builtin_amdgcn_mfma_f32_16x16x32_bf16(ah1[ks_], BL[ks_], aX1_, 0, 0, 0); \
            aX0_ = __builtin_amdgcn_mfma_f32_16x16x32_bf16(al0[ks_], BH[ks_], aX0_, 0, 0, 0); \
            aX1_ = __builtin_amdgcn_mfma_f32_16x16x32_bf16(al1[ks_], BH[ks_], aX1_, 0, 0, 0); \
        }                                                                      \
        d0 = aH0_ + aX0_;                                                      \
        d1 = aH1_ + aX1_;                                                      \
    }

#define GEMM_LAYER(hiBase, loBase)                                             \
    LOADB(Bh0, Bl0, hiBase, loBase, 0)                                         \
    LOADB(Bh1, Bl1, hiBase, loBase, 1)                                         \
    __builtin_amdgcn_sched_barrier(0);                                         \
    COMPB2(Bh0, Bl0, acc0[0], acc1[0])                                         \
    LOADB(Bh0, Bl0, hiBase, loBase, 2)                                         \
    __builtin_amdgcn_sched_barrier(0);                                         \
    COMPB2(Bh1, Bl1, acc0[1], acc1[1])                                         \
    LOADB(Bh1, Bl1, hiBase, loBase, 3)                                         \
    __builtin_amdgcn_sched_barrier(0);                                         \
    COMPB2(Bh0, Bl0, acc0[2], acc1[2])                                         \
    LOADB(Bh0, Bl0, hiBase, loBase, 4)                                         \
    __builtin_amdgcn_sched_barrier(0);                                         \
    COMPB2(Bh1, Bl1, acc0[3], acc1[3])                                         \
    LOADB(Bh1, Bl1, hiBase, loBase, 5)                                         \
    __builtin_amdgcn_sched_barrier(0);                                         \
    COMPB2(Bh0, Bl0, acc0[4], acc1[4])                                         \
    LOADB(Bh0, Bl0, hiBase, loBase, 6)                                         \
    __builtin_amdgcn_sched_barrier(0);                                         \
    COMPB2(Bh1, Bl1, acc0[5], acc1[5])                                         \
    LOADB(Bh1, Bl1, hiBase, loBase, 7)                                         \
    __builtin_amdgcn_sched_barrier(0);                                         \
    COMPB2(Bh0, Bl0, acc0[6], acc1[6])                                         \
    COMPB2(Bh1, Bl1, acc0[7], acc1[7])

#define LN1_TILE(ACC, HLP)                                                     \
    {                                                                          \
        _Pragma("unroll")                                                      \
        for (int j = 0; j < 4; ++j) {                                          \
            float t_[8], s_ = 0.f, ss_ = 0.f;                                  \
            _Pragma("unroll")                                                  \
            for (int ct = 0; ct < 8; ++ct) {                                   \
                t_[ct] = ACC[ct][j] + b1v[ct];                                 \
                s_ += t_[ct]; ss_ += t_[ct] * t_[ct];                          \
            }                                                                  \
            _Pragma("unroll")                                                  \
            for (int off = 1; off <= 8; off <<= 1) {                           \
                s_  += __shfl_xor(s_,  off, 16);                               \
                ss_ += __shfl_xor(ss_, off, 16);                               \
            }                                                                  \
            const float mu_   = s_ * (1.f / 128.f);                            \
            const float var_  = fmaxf(ss_ * (1.f / 128.f) - mu_ * mu_, 0.f);   \
            const float rstd_ = rsqrtf(var_ + 1e-6f);                          \
            const int row_ = lg * 4 + j;                                       \
            _Pragma("unroll")                                                  \
            for (int ct = 0; ct < 8; ++ct) {                                   \
                const float o_ = fmaxf((t_[ct] - mu_) * rstd_ * g1v[ct] + t1v[ct], 0.f); \
                const unsigned short hh_ = bf16h(o_);                          \
                const unsigned short ll_ = bf16h(o_ - bf16tof(hh_));           \
                HLP[row_ * PW + ct * 16 + lc] = (unsigned)hh_ | ((unsigned)ll_ << 16); \
            }                                                                  \
        }                                                                      \
    }

#define LOADA2(AH, AL, HLP)                                                    \
    _Pragma("unroll")                                                          \
    for (int ks_ = 0; ks_ < 4; ++ks_) {                                        \
        const uint4 r0_ = *(const uint4*)&HLP[lc * PW + ks_ * 32 + lg * 8];    \
        const uint4 r1_ = *(const uint4*)&HLP[lc * PW + ks_ * 32 + lg * 8 + 4];\
        const unsigned rr_[8] = {r0_.x, r0_.y, r0_.z, r0_.w,                   \
                                 r1_.x, r1_.y, r1_.z, r1_.w};                  \
        _Pragma("unroll")                                                      \
        for (int i_ = 0; i_ < 8; ++i_) {                                       \
            AH[ks_][i_] = (short)(rr_[i_] & 0xffffu);                          \
            AL[ks_][i_] = (short)(rr_[i_] >> 16);                              \
        }                                                                      \
    }

#define LN2_TILE(ACC, ROWBASE)                                                 \
    {                                                                          \
        _Pragma("unroll")                                                      \
        for (int j = 0; j < 4; ++j) {                                          \
            float t_[8], s_ = 0.f, ss_ = 0.f;                                  \
            _Pragma("unroll")                                                  \
            for (int ct = 0; ct < 8; ++ct) {                                   \
                t_[ct] = ACC[ct][j] + b2v[ct];                                 \
                s_ += t_[ct]; ss_ += t_[ct] * t_[ct];                          \
            }                                                                  \
            _Pragma("unroll")                                                  \
            for (int off = 1; off <= 8; off <<= 1) {                           \
                s_  += __shfl_xor(s_,  off, 16);                               \
                ss_ += __shfl_xor(ss_, off, 16);                               \
            }                                                                  \
            const float mu_   = s_ * (1.f / 128.f);                            \
            const float var_  = fmaxf(ss_ * (1.f / 128.f) - mu_ * mu_, 0.f);   \
            const float rstd_ = rsqrtf(var_ + 1e-6f);                          \
            const int grow_ = (ROWBASE) + lg * 4 + j;                          \
            if (grow_ < N) {                                                   \
                _Pragma("unroll")                                              \
                for (int ct = 0; ct < 8; ++ct) {                               \
                    const float o_ = fmaxf((t_[ct] - mu_) * rstd_ * g2v[ct] + t2v[ct], 0.f); \
                    Q[(size_t)grow_ * 128 + ct * 16 + lc] = bf16h(o_);         \
                }                                                              \
            }                                                                  \
        }                                                                      \
    }

    // ---- hoist LN params ----
    float b1v[8], g1v[8], t1v[8], b2v[8], g2v[8], t2v[8];
    #pragma unroll
    for (int ct = 0; ct < 8; ++ct) {
        const int col = ct * 16 + lc;
        b1v[ct] = b1[col]; g1v[ct] = g1[col]; t1v[ct] = be1[col];
        b2v[ct] = b2[col]; g2v[ct] = g2[col]; t2v[ct] = be2[col];
    }

    // ================= layer 1 =================
    GEMM_LAYER(0, 32)

    LN1_TILE(acc0, hl0)
    LN1_TILE(acc1, hl1)

    asm volatile("s_waitcnt lgkmcnt(0)" ::: "memory");
    __builtin_amdgcn_sched_barrier(0);

    LOADA2(ah0, al0, hl0)
    LOADA2(ah1, al1, hl1)

    // ================= layer 2 =================
    GEMM_LAYER(64, 96)

    LN2_TILE(acc0, n0w)
    LN2_TILE(acc1, n0w + 16)

#undef LN2_TILE
#undef LOADA2
#undef LN1_TILE
#undef GEMM_LAYER
#undef COMPB2
#undef LOADB
}

// ---- CSR build: per-1024-chunk exclusive scan ----
__global__ __launch_bounds__(256) void scan_blocks_kernel(
    const int* __restrict__ cnt, int* __restrict__ rowptr,
    int* __restrict__ bsum, int N)
{
    __shared__ int lds[256];
    const int tid = threadIdx.x;
    const int base = blockIdx.x * 1024 + tid * 4;
    int v0 = (base + 0 < N) ? cnt[base + 0] : 0;
    int v1 = (base + 1 < N) ? cnt[base + 1] : 0;
    int v2 = (base + 2 < N) ? cnt[base + 2] : 0;
    int v3 = (base + 3 < N) ? cnt[base + 3] : 0;
    const int tsum = v0 + v1 + v2 + v3;
    lds[tid] = tsum;
    __syncthreads();
    for (int off = 1; off < 256; off <<= 1) {
        int t = (tid >= off) ? lds[tid - off] : 0;
        __syncthreads();
        lds[tid] += t;
        __syncthreads();
    }
    int run = lds[tid] - tsum;
    if (base + 0 < N) rowptr[base + 0] = run;
    run += v0;
    if (base + 1 < N) rowptr[base + 1] = run;
    run += v1;
    if (base + 2 < N) rowptr[base + 2] = run;
    run += v2;
    if (base + 3 < N) rowptr[base + 3] = run;
    if (tid == 255) bsum[blockIdx.x] = lds[255];
}

// ---- CSR build: scan block sums ----
__global__ __launch_bounds__(256) void scan_top_kernel(int* bsum, int nb)
{
    __shared__ int lds[256];
    const int tid = threadIdx.x;
    int v = (tid < nb) ? bsum[tid] : 0;
    lds[tid] = v;
    __syncthreads();
    for (int off = 1; off < 256; off <<= 1) {
        int t = (tid >= off) ? lds[tid - off] : 0;
        __syncthreads();
        lds[tid] += t;
        __syncthreads();
    }
    if (tid < nb) bsum[tid] = lds[tid] - v;
}

// ---- CSR build: add chunk offsets ----
__global__ __launch_bounds__(256) void scan_add_kernel(
    int* __restrict__ rowptr, int* __restrict__ cursor,
    const int* __restrict__ bsum, int N, int E)
{
    int i = blockIdx.x * blockDim.x + threadIdx.x;
    if (i < N) {
        int v = rowptr[i] + bsum[i >> 10];
        rowptr[i] = v;
        cursor[i] = v;
    }
    if (i == 0) rowptr[N] = E;
}

// ---- CSR build: bucket-fill sorted sender ids ----
__global__ __launch_bounds__(256) void fill_kernel(
    const int* __restrict__ senders, const int* __restrict__ receivers,
    int* __restrict__ cursor, int* __restrict__ ssend, int E)
{
    int e = blockIdx.x * blockDim.x + threadIdx.x;
    if (e < E) {
        int r = receivers[e];
        int pos = atomicAdd(&cursor[r], 1);
        ssend[pos] = senders[e];
    }
}

// ---- fused per-node attention (bf16 q), DUAL-STREAM per half ----
__global__ __launch_bounds__(256) void node_attn_kernel(
    const unsigned short* __restrict__ q, const int* __restrict__ rowptr,
    const int* __restrict__ ssend, float* __restrict__ out, int N)
{
    const int lane = threadIdx.x & 63;
    const int hl   = lane & 31;
    const int half = lane >> 5;
    const int wid  = (blockIdx.x * blockDim.x + threadIdx.x) >> 6;
    const int nw   = (gridDim.x * blockDim.x) >> 6;

    for (int n = wid; n < N; n += nw) {
        const uint2 braw = *(const uint2*)&q[(size_t)n * D + hl * 4];
        const float b0 = __uint_as_float(braw.x << 16);
        const float b1 = __uint_as_float(braw.x & 0xffff0000u);
        const float b2 = __uint_as_float(braw.y << 16);
        const float b3 = __uint_as_float(braw.y & 0xffff0000u);

        const int beg = rowptr[n], end = rowptr[n + 1];

        float mA = -1e30f, lA = 0.f, cA0 = 0.f, cA1 = 0.f, cA2 = 0.f, cA3 = 0.f;
        float mB = -1e30f, lB = 0.f, cB0 = 0.f, cB1 = 0.f, cB2 = 0.f, cB3 = 0.f;

        auto step = [&](uint2 c, float& m, float& l,
                        float& s0r, float& s1r, float& s2r, float& s3r) {
            const float a0 = __uint_as_float(c.x << 16);
            const float a1 = __uint_as_float(c.x & 0xffff0000u);
            const float a2 = __uint_as_float(c.y << 16);
            const float a3 = __uint_as_float(c.y & 0xffff0000u);
            float p = a0 * b0 + a1 * b1 + a2 * b2 + a3 * b3;
            p += __shfl_xor(p, 1);
            p += __shfl_xor(p, 2);
            p += __shfl_xor(p, 4);
            const float logit = p * 0.17677669529663687f;   // 1/sqrt(32)
            const float nm = fmaxf(m, logit);
            const float sc = __expf(m - nm);
            const float u  = __expf(logit - nm);
            l   = l   * sc + u;
            s0r = s0r * sc + u * a0;
            s1r = s1r * sc + u * a1;
            s2r = s2r * sc + u * a2;
            s3r = s3r * sc + u * a3;
            m = nm;
        };

        int jA = beg + half;
        int jB = jA + 2;
        uint2 rA = {0u, 0u}, rB = {0u, 0u};
        if (jA < end) rA = *(const uint2*)&q[(size_t)ssend[jA] * D + hl * 4];
        if (jB < end) rB = *(const uint2*)&q[(size_t)ssend[jB] * D + hl * 4];

        for (; jB < end; jA += 4, jB += 4) {
            const uint2 cA = rA, cB = rB;
            if (jA + 4 < end)
                rA = *(const uint2*)&q[(size_t)ssend[jA + 4] * D + hl * 4];
            if (jB + 4 < end)
                rB = *(const uint2*)&q[(size_t)ssend[jB + 4] * D + hl * 4];
            step(cA, mA, lA, cA0, cA1, cA2, cA3);
            step(cB, mB, lB, cB0, cB1, cB2, cB3);
        }
        if (jA < end)
            step(rA, mA, lA, cA0, cA1, cA2, cA3);

        // merge stream B into A (in-lane flash merge)
        {
            const float nm = fmaxf(mA, mB);
            const float s0 = __expf(mA - nm), s1 = __expf(mB - nm);
            lA  = lA  * s0 + lB  * s1;
            cA0 = cA0 * s0 + cB0 * s1;
            cA1 = cA1 * s0 + cB1 * s1;
            cA2 = cA2 * s0 + cB2 * s1;
            cA3 = cA3 * s0 + cB3 * s1;
            mA = nm;
        }

        // merge the two halves' states (flash-attention merge)
        const float om  = __shfl_xor(mA, 32);
        const float ol  = __shfl_xor(lA, 32);
        const float oc0 = __shfl_xor(cA0, 32);
        const float oc1 = __shfl_xor(cA1, 32);
        const float oc2 = __shfl_xor(cA2, 32);
        const float oc3 = __shfl_xor(cA3, 32);
        const float nm = fmaxf(mA, om);
        const float s0 = __expf(mA - nm), s1 = __expf(om - nm);
        const float lt = lA * s0 + ol * s1;
        const float inv = (lt > 0.f) ? (1.f / lt) : 0.f;
        float r0 = fmaxf((cA0 * s0 + oc0 * s1) * inv, 0.f);
        float r1 = fmaxf((cA1 * s0 + oc1 * s1) * inv, 0.f);
        float r2 = fmaxf((cA2 * s0 + oc2 * s1) * inv, 0.f);
        float r3 = fmaxf((cA3 * s0 + oc3 * s1) * inv, 0.f);

        // head-mean: lanes hl, hl^8, hl^16, hl^24 hold heads 0..3 of same f
        r0 += __shfl_xor(r0, 8);  r0 += __shfl_xor(r0, 16);
        r1 += __shfl_xor(r1, 8);  r1 += __shfl_xor(r1, 16);
        r2 += __shfl_xor(r2, 8);  r2 += __shfl_xor(r2, 16);
        r3 += __shfl_xor(r3, 8);  r3 += __shfl_xor(r3, 16);
        if (lane < 8) {
            float4 o = {0.25f * r0, 0.25f * r1, 0.25f * r2, 0.25f * r3};
            *(float4*)&out[(size_t)n * NF + lane * 4] = o;
        }
    }
}

extern "C" void kernel_launch(void* const* d_in, const int* in_sizes, int n_in,
                              void* d_out, int out_size, void* d_ws, size_t ws_size,
                              hipStream_t stream)
{
    const float* nodes = (const float*)d_in[0];
    const float* W1    = (const float*)d_in[1];
    const float* b1    = (const float*)d_in[2];
    const float* g1    = (const float*)d_in[3];
    const float* be1   = (const float*)d_in[4];
    const float* W2    = (const float*)d_in[5];
    const float* b2    = (const float*)d_in[6];
    const float* g2    = (const float*)d_in[7];
    const float* be2   = (const float*)d_in[8];
    const int* senders   = (const int*)d_in[9];
    const int* receivers = (const int*)d_in[10];

    const int N = in_sizes[0] / D;
    const int E = in_sizes[9];
    float* out = (float*)d_out;

    char* ws = (char*)d_ws;
    unsigned short* qb = (unsigned short*)ws; ws += (size_t)N * D * 2;
    unsigned short* wt = (unsigned short*)ws; ws += 4 * 128 * 128 * 2;
    int* cnt      = (int*)ws;    ws += (size_t)N * 4;
    int* rowptr   = (int*)ws;    ws += (size_t)(N + 2) * 4;
    int* cursor   = (int*)ws;    ws += (size_t)N * 4;
    int* bsum     = (int*)ws;    ws += 256 * 4;
    int* ssend    = (int*)ws;    ws += (size_t)E * 4;

    const int zb = (N + 1023) / 1024;
    const int nwt32 = (N + 31) / 32;
    const int mlpBlocks = (nwt32 + 3) / 4;
    const int nb = (N + 1023) / 1024;

    // 1: weight split + counter zero
    prep_kernel<<<16 + zb, 256, 0, stream>>>(W1, W2, wt, cnt, N);

    // 2: 32-rows/wave MFMA MLP + edge histogram (tail blocks)
    mlp_hist_kernel<<<mlpBlocks + 128, 256, 0, stream>>>(
        nodes, wt, b1, g1, be1, b2, g2, be2, qb, N,
        receivers, cnt, E, mlpBlocks);

    // 3-5: CSR scan
    scan_blocks_kernel<<<nb, 256, 0, stream>>>(cnt, rowptr, bsum, N);
    scan_top_kernel<<<1, 256, 0, stream>>>(bsum, nb);
    scan_add_kernel<<<(N + 255) / 256, 256, 0, stream>>>(rowptr, cursor, bsum, N, E);

    // 6: bucket-fill receiver-sorted sender list
    fill_kernel<<<(E + 255) / 256, 256, 0, stream>>>(senders, receivers, cursor, ssend, E);

    // 7: dual-stream fused attention + epilogue
    node_attn_kernel<<<(N + 3) / 4, 256, 0, stream>>>(qb, rowptr, ssend, out, N);
}

// Round 17
// 114.298 us; speedup vs baseline: 1.1084x; 1.0255x over previous
//
#include <hip/hip_runtime.h>

constexpr int D  = 128;   // feature dim (= H*F)
constexpr int NH = 4;     // heads
constexpr int NF = 32;    // features per head

typedef __attribute__((ext_vector_type(8))) short bfrag;   // 8 bf16 = 4 VGPR
typedef __attribute__((ext_vector_type(4))) float ffrag;   // 4 f32 acc

// bf16 RNE helpers
__device__ __forceinline__ unsigned short bf16h(float x) {
    unsigned u = __float_as_uint(x);
    u += 0x7fffu + ((u >> 16) & 1u);
    return (unsigned short)(u >> 16);
}
__device__ __forceinline__ float bf16tof(unsigned short h) {
    return __uint_as_float(((unsigned)h) << 16);
}

// ---- launch 1: wsplit (blocks 0..15) + zero counters (blocks 16..) ----
__global__ __launch_bounds__(256) void prep_kernel(
    const float* __restrict__ W1, const float* __restrict__ W2,
    unsigned short* __restrict__ wt, int* __restrict__ cnt, int nz)
{
    if (blockIdx.x < 16) {
        const int L  = blockIdx.x >> 3;
        const int ct = blockIdx.x & 7;
        const float* W = L ? W2 : W1;
        const int ks   = threadIdx.x >> 6;
        const int lane = threadIdx.x & 63;
        const int lg = lane >> 4, lc = lane & 15;
        unsigned short* Hp = wt + ((size_t)(L * 2 + 0) * 32 + ct * 4 + ks) * 512 + lane * 8;
        unsigned short* Lp = wt + ((size_t)(L * 2 + 1) * 32 + ct * 4 + ks) * 512 + lane * 8;
        #pragma unroll
        for (int i = 0; i < 8; ++i) {
            const int k = ks * 32 + lg * 8 + i;
            const int c = ct * 16 + lc;
            const float v = W[(size_t)k * 128 + c];
            const unsigned short hh = bf16h(v);
            Hp[i] = hh;
            Lp[i] = bf16h(v - bf16tof(hh));
        }
    } else {
        const int i4 = ((blockIdx.x - 16) * 256 + threadIdx.x) * 4;
        if (i4 + 3 < nz) {
            *(int4*)&cnt[i4] = {0, 0, 0, 0};
        } else if (i4 < nz) {
            for (int i = i4; i < nz; ++i) cnt[i] = 0;
        }
    }
}

// ---- launch 2: MFMA MLP, 32 rows/wave (2 tiles share B) + histogram tail ----
// R10's exact kernel (best measured total). Each wave owns TWO 16-row
// tiles that share every B-fragment. 1563 waves x 16 B-batches.
__global__ __launch_bounds__(256, 2) void mlp_hist_kernel(
    const float* __restrict__ X,
    const unsigned short* __restrict__ WF,
    const float* __restrict__ b1, const float* __restrict__ g1, const float* __restrict__ be1,
    const float* __restrict__ b2, const float* __restrict__ g2, const float* __restrict__ be2,
    unsigned short* __restrict__ Q, int N,
    const int* __restrict__ recv, int* __restrict__ cnt, int E, int mlpBlocks)
{
    constexpr int PW = 132;                    // u32 pitch (528B, b128-aligned)
    __shared__ unsigned HL[4 * 2 * 16 * PW];   // 67584 B: [wave][tile][row][k]

    if (blockIdx.x >= mlpBlocks) {
        // ---- histogram role (runs as CUs free up) ----
        const int tid0   = (blockIdx.x - mlpBlocks) * 256 + threadIdx.x;
        const int stride = (gridDim.x - mlpBlocks) * 256;
        for (int i = tid0; i < E; i += stride) atomicAdd(&cnt[recv[i]], 1);
        return;
    }

    const int tid  = threadIdx.x;
    const int lane = tid & 63;
    const int wave = tid >> 6;
    const int lc   = lane & 15;
    const int lg   = lane >> 4;
    const int n0w  = (blockIdx.x * 4 + wave) * 32;   // 32 rows per wave
    if (n0w >= N) return;
    unsigned* hl0 = &HL[(wave * 2 + 0) * 16 * PW];
    unsigned* hl1 = &HL[(wave * 2 + 1) * 16 * PW];

    bfrag ah0[4], al0[4], ah1[4], al1[4];

    // ---- A-frags layer 1 for both tiles: from global X, split in-reg ----
    #pragma unroll
    for (int t = 0; t < 2; ++t) {
        const int row = n0w + t * 16 + lc;
        const int rowx = (row < N) ? row : (N - 1);
        const float* xr = X + (size_t)rowx * 128 + lg * 8;
        #pragma unroll
        for (int ks = 0; ks < 4; ++ks) {
            const float4 a = *(const float4*)&xr[ks * 32];
            const float4 b = *(const float4*)&xr[ks * 32 + 4];
            const float f[8] = {a.x, a.y, a.z, a.w, b.x, b.y, b.z, b.w};
            #pragma unroll
            for (int i = 0; i < 8; ++i) {
                const unsigned short hh = bf16h(f[i]);
                const unsigned short ll = bf16h(f[i] - bf16tof(hh));
                if (t == 0) { ah0[ks][i] = (short)hh; al0[ks][i] = (short)ll; }
                else        { ah1[ks][i] = (short)hh; al1[ks][i] = (short)ll; }
            }
        }
    }

    bfrag Bh0[4], Bl0[4], Bh1[4], Bl1[4];      // two B buffers (32 VGPR each)
    ffrag acc0[8], acc1[8];

#define LOADB(BH, BL, hiBase, loBase, ctg)                                     \
    {                                                                          \
        const unsigned short* hp_ = WF + (size_t)((hiBase) + (ctg) * 4) * 512 + lane * 8; \
        const unsigned short* lp_ = WF + (size_t)((loBase) + (ctg) * 4) * 512 + lane * 8; \
        _Pragma("unroll")                                                      \
        for (int ks_ = 0; ks_ < 4; ++ks_) {                                    \
            BH[ks_] = *(const bfrag*)(hp_ + ks_ * 512);                        \
            BL[ks_] = *(const bfrag*)(lp_ + ks_ * 512);                        \
        }                                                                      \
    }

#define COMPB2(BH, BL, d0, d1)                                                 \
    {                                                                          \
        ffrag aH0_ = (ffrag){0.f,0.f,0.f,0.f}, aX0_ = (ffrag){0.f,0.f,0.f,0.f};\
        ffrag aH1_ = (ffrag){0.f,0.f,0.f,0.f}, aX1_ = (ffrag){0.f,0.f,0.f,0.f};\
        _Pragma("unroll")                                                      \
        for (int ks_ = 0; ks_ < 4; ++ks_) {                                    \
            aH0_ = __builtin_amdgcn_mfma_f32_16x16x32_bf16(ah0[ks_], BH[ks_], aH0_, 0, 0, 0); \
            aH1_ = __builtin_amdgcn_mfma_f32_16x16x32_bf16(ah1[ks_], BH[ks_], aH1_, 0, 0, 0); \
            aX0_ = __builtin_amdgcn_mfma_f32_16x16x32_bf16(ah0[ks_], BL[ks_], aX0_, 0, 0, 0); \
            aX1_ = __builtin_amdgcn_mfma_f32_16x16x32_bf16(ah1[ks_], BL[ks_], aX1_, 0, 0, 0); \
            aX0_ = __builtin_amdgcn_mfma_f32_16x16x32_bf16(al0[ks_], BH[ks_], aX0_, 0, 0, 0); \
            aX1_ = __builtin_amdgcn_mfma_f32_16x16x32_bf16(al1[ks_], BH[ks_], aX1_, 0, 0, 0); \
        }                                                                      \
        d0 = aH0_ + aX0_;                                                      \
        d1 = aH1_ + aX1_;                                                      \
    }

#define GEMM_LAYER(hiBase, loBase)                                             \
    LOADB(Bh0, Bl0, hiBase, loBase, 0)                                         \
    LOADB(Bh1, Bl1, hiBase, loBase, 1)                                         \
    __builtin_amdgcn_sched_barrier(0);                                         \
    COMPB2(Bh0, Bl0, acc0[0], acc1[0])                                         \
    LOADB(Bh0, Bl0, hiBase, loBase, 2)                                         \
    __builtin_amdgcn_sched_barrier(0);                                         \
    COMPB2(Bh1, Bl1, acc0[1], acc1[1])                                         \
    LOADB(Bh1, Bl1, hiBase, loBase, 3)                                         \
    __builtin_amdgcn_sched_barrier(0);                                         \
    COMPB2(Bh0, Bl0, acc0[2], acc1[2])                                         \
    LOADB(Bh0, Bl0, hiBase, loBase, 4)                                         \
    __builtin_amdgcn_sched_barrier(0);                                         \
    COMPB2(Bh1, Bl1, acc0[3], acc1[3])                                         \
    LOADB(Bh1, Bl1, hiBase, loBase, 5)                                         \
    __builtin_amdgcn_sched_barrier(0);                                         \
    COMPB2(Bh0, Bl0, acc0[4], acc1[4])                                         \
    LOADB(Bh0, Bl0, hiBase, loBase, 6)                                         \
    __builtin_amdgcn_sched_barrier(0);                                         \
    COMPB2(Bh1, Bl1, acc0[5], acc1[5])                                         \
    LOADB(Bh1, Bl1, hiBase, loBase, 7)                                         \
    __builtin_amdgcn_sched_barrier(0);                                         \
    COMPB2(Bh0, Bl0, acc0[6], acc1[6])                                         \
    COMPB2(Bh1, Bl1, acc0[7], acc1[7])

#define LN1_TILE(ACC, HLP)                                                     \
    {                                                                          \
        _Pragma("unroll")                                                      \
        for (int j = 0; j < 4; ++j) {                                          \
            float t_[8], s_ = 0.f, ss_ = 0.f;                                  \
            _Pragma("unroll")                                                  \
            for (int ct = 0; ct < 8; ++ct) {                                   \
                t_[ct] = ACC[ct][j] + b1v[ct];                                 \
                s_ += t_[ct]; ss_ += t_[ct] * t_[ct];                          \
            }                                                                  \
            _Pragma("unroll")                                                  \
            for (int off = 1; off <= 8; off <<= 1) {                           \
                s_  += __shfl_xor(s_,  off, 16);                               \
                ss_ += __shfl_xor(ss_, off, 16);                               \
            }                                                                  \
            const float mu_   = s_ * (1.f / 128.f);                            \
            const float var_  = fmaxf(ss_ * (1.f / 128.f) - mu_ * mu_, 0.f);   \
            const float rstd_ = rsqrtf(var_ + 1e-6f);                          \
            const int row_ = lg * 4 + j;                                       \
            _Pragma("unroll")                                                  \
            for (int ct = 0; ct < 8; ++ct) {                                   \
                const float o_ = fmaxf((t_[ct] - mu_) * rstd_ * g1v[ct] + t1v[ct], 0.f); \
                const unsigned short hh_ = bf16h(o_);                          \
                const unsigned short ll_ = bf16h(o_ - bf16tof(hh_));           \
                HLP[row_ * PW + ct * 16 + lc] = (unsigned)hh_ | ((unsigned)ll_ << 16); \
            }                                                                  \
        }                                                                      \
    }

#define LOADA2(AH, AL, HLP)                                                    \
    _Pragma("unroll")                                                          \
    for (int ks_ = 0; ks_ < 4; ++ks_) {                                        \
        const uint4 r0_ = *(const uint4*)&HLP[lc * PW + ks_ * 32 + lg * 8];    \
        const uint4 r1_ = *(const uint4*)&HLP[lc * PW + ks_ * 32 + lg * 8 + 4];\
        const unsigned rr_[8] = {r0_.x, r0_.y, r0_.z, r0_.w,                   \
                                 r1_.x, r1_.y, r1_.z, r1_.w};                  \
        _Pragma("unroll")                                                      \
        for (int i_ = 0; i_ < 8; ++i_) {                                       \
            AH[ks_][i_] = (short)(rr_[i_] & 0xffffu);                          \
            AL[ks_][i_] = (short)(rr_[i_] >> 16);                              \
        }                                                                      \
    }

#define LN2_TILE(ACC, ROWBASE)                                                 \
    {                                                                          \
        _Pragma("unroll")                                                      \
        for (int j = 0; j < 4; ++j) {                                          \
            float t_[8], s_ = 0.f, ss_ = 0.f;                                  \
            _Pragma("unroll")                                                  \
            for (int ct = 0; ct < 8; ++ct) {                                   \
                t_[ct] = ACC[ct][j] + b2v[ct];                                 \
                s_ += t_[ct]; ss_ += t_[ct] * t_[ct];                          \
            }                                                                  \
            _Pragma("unroll")                                                  \
            for (int off = 1; off <= 8; off <<= 1) {                           \
                s_  += __shfl_xor(s_,  off, 16);                               \
                ss_ += __shfl_xor(ss_, off, 16);                               \
            }                                                                  \
            const float mu_   = s_ * (1.f / 128.f);                            \
            const float var_  = fmaxf(ss_ * (1.f / 128.f) - mu_ * mu_, 0.f);   \
            const float rstd_ = rsqrtf(var_ + 1e-6f);                          \
            const int grow_ = (ROWBASE) + lg * 4 + j;                          \
            if (grow_ < N) {                                                   \
                _Pragma("unroll")                                              \
                for (int ct = 0; ct < 8; ++ct) {                               \
                    const float o_ = fmaxf((t_[ct] - mu_) * rstd_ * g2v[ct] + t2v[ct], 0.f); \
                    Q[(size_t)grow_ * 128 + ct * 16 + lc] = bf16h(o_);         \
                }                                                              \
            }                                                                  \
        }                                                                      \
    }

    // ---- hoist LN params ----
    float b1v[8], g1v[8], t1v[8], b2v[8], g2v[8], t2v[8];
    #pragma unroll
    for (int ct = 0; ct < 8; ++ct) {
        const int col = ct * 16 + lc;
        b1v[ct] = b1[col]; g1v[ct] = g1[col]; t1v[ct] = be1[col];
        b2v[ct] = b2[col]; g2v[ct] = g2[col]; t2v[ct] = be2[col];
    }

    // ================= layer 1 =================
    GEMM_LAYER(0, 32)

    LN1_TILE(acc0, hl0)
    LN1_TILE(acc1, hl1)

    asm volatile("s_waitcnt lgkmcnt(0)" ::: "memory");
    __builtin_amdgcn_sched_barrier(0);

    LOADA2(ah0, al0, hl0)
    LOADA2(ah1, al1, hl1)

    // ================= layer 2 =================
    GEMM_LAYER(64, 96)

    LN2_TILE(acc0, n0w)
    LN2_TILE(acc1, n0w + 16)

#undef LN2_TILE
#undef LOADA2
#undef LN1_TILE
#undef GEMM_LAYER
#undef COMPB2
#undef LOADB
}

// ---- CSR build: per-1024-chunk exclusive scan ----
__global__ __launch_bounds__(256) void scan_blocks_kernel(
    const int* __restrict__ cnt, int* __restrict__ rowptr,
    int* __restrict__ bsum, int N)
{
    __shared__ int lds[256];
    const int tid = threadIdx.x;
    const int base = blockIdx.x * 1024 + tid * 4;
    int v0 = (base + 0 < N) ? cnt[base + 0] : 0;
    int v1 = (base + 1 < N) ? cnt[base + 1] : 0;
    int v2 = (base + 2 < N) ? cnt[base + 2] : 0;
    int v3 = (base + 3 < N) ? cnt[base + 3] : 0;
    const int tsum = v0 + v1 + v2 + v3;
    lds[tid] = tsum;
    __syncthreads();
    for (int off = 1; off < 256; off <<= 1) {
        int t = (tid >= off) ? lds[tid - off] : 0;
        __syncthreads();
        lds[tid] += t;
        __syncthreads();
    }
    int run = lds[tid] - tsum;
    if (base + 0 < N) rowptr[base + 0] = run;
    run += v0;
    if (base + 1 < N) rowptr[base + 1] = run;
    run += v1;
    if (base + 2 < N) rowptr[base + 2] = run;
    run += v2;
    if (base + 3 < N) rowptr[base + 3] = run;
    if (tid == 255) bsum[blockIdx.x] = lds[255];
}

// ---- CSR build: scan block sums ----
__global__ __launch_bounds__(256) void scan_top_kernel(int* bsum, int nb)
{
    __shared__ int lds[256];
    const int tid = threadIdx.x;
    int v = (tid < nb) ? bsum[tid] : 0;
    lds[tid] = v;
    __syncthreads();
    for (int off = 1; off < 256; off <<= 1) {
        int t = (tid >= off) ? lds[tid - off] : 0;
        __syncthreads();
        lds[tid] += t;
        __syncthreads();
    }
    if (tid < nb) bsum[tid] = lds[tid] - v;
}

// ---- CSR build: add chunk offsets ----
__global__ __launch_bounds__(256) void scan_add_kernel(
    int* __restrict__ rowptr, int* __restrict__ cursor,
    const int* __restrict__ bsum, int N, int E)
{
    int i = blockIdx.x * blockDim.x + threadIdx.x;
    if (i < N) {
        int v = rowptr[i] + bsum[i >> 10];
        rowptr[i] = v;
        cursor[i] = v;
    }
    if (i == 0) rowptr[N] = E;
}

// ---- CSR build: bucket-fill sorted sender ids ----
__global__ __launch_bounds__(256) void fill_kernel(
    const int* __restrict__ senders, const int* __restrict__ receivers,
    int* __restrict__ cursor, int* __restrict__ ssend, int E)
{
    int e = blockIdx.x * blockDim.x + threadIdx.x;
    if (e < E) {
        int r = receivers[e];
        int pos = atomicAdd(&cursor[r], 1);
        ssend[pos] = senders[e];
    }
}

// ---- fused per-node attention (bf16 q), ONE NODE PER 32-LANE HALF ----
// A 32-lane half covers all 128 dims (4/lane), so it is self-sufficient for
// one node: dot-reduce within 8-lane head groups (shfl 1,2,4), head-mean via
// shfl 8,16 — all intra-half. Assigning each half its OWN node removes the
// cross-half flash-merge (6 shfl + ~15 VALU) and the duplicated q-row load,
// halving the per-node fixed cost. Dual-stream (stride 2) kept per half for
// gather MLP. Loop traffic unchanged (256B/edge).
__global__ __launch_bounds__(256) void node_attn_kernel(
    const unsigned short* __restrict__ q, const int* __restrict__ rowptr,
    const int* __restrict__ ssend, float* __restrict__ out, int N)
{
    const int hl  = threadIdx.x & 31;
    const int hid = (blockIdx.x * blockDim.x + threadIdx.x) >> 5;   // half index
    const int nh  = (gridDim.x * blockDim.x) >> 5;

    for (int n = hid; n < N; n += nh) {
        const uint2 braw = *(const uint2*)&q[(size_t)n * D + hl * 4];
        const float b0 = __uint_as_float(braw.x << 16);
        const float b1 = __uint_as_float(braw.x & 0xffff0000u);
        const float b2 = __uint_as_float(braw.y << 16);
        const float b3 = __uint_as_float(braw.y & 0xffff0000u);

        const int beg = rowptr[n], end = rowptr[n + 1];

        float mA = -1e30f, lA = 0.f, cA0 = 0.f, cA1 = 0.f, cA2 = 0.f, cA3 = 0.f;
        float mB = -1e30f, lB = 0.f, cB0 = 0.f, cB1 = 0.f, cB2 = 0.f, cB3 = 0.f;

        auto step = [&](uint2 c, float& m, float& l,
                        float& s0r, float& s1r, float& s2r, float& s3r) {
            const float a0 = __uint_as_float(c.x << 16);
            const float a1 = __uint_as_float(c.x & 0xffff0000u);
            const float a2 = __uint_as_float(c.y << 16);
            const float a3 = __uint_as_float(c.y & 0xffff0000u);
            float p = a0 * b0 + a1 * b1 + a2 * b2 + a3 * b3;
            p += __shfl_xor(p, 1);
            p += __shfl_xor(p, 2);
            p += __shfl_xor(p, 4);
            const float logit = p * 0.17677669529663687f;   // 1/sqrt(32)
            const float nm = fmaxf(m, logit);
            const float sc = __expf(m - nm);
            const float u  = __expf(logit - nm);
            l   = l   * sc + u;
            s0r = s0r * sc + u * a0;
            s1r = s1r * sc + u * a1;
            s2r = s2r * sc + u * a2;
            s3r = s3r * sc + u * a3;
            m = nm;
        };

        int jA = beg;
        int jB = beg + 1;
        uint2 rA = {0u, 0u}, rB = {0u, 0u};
        if (jA < end) rA = *(const uint2*)&q[(size_t)ssend[jA] * D + hl * 4];
        if (jB < end) rB = *(const uint2*)&q[(size_t)ssend[jB] * D + hl * 4];

        for (; jB < end; jA += 2, jB += 2) {
            const uint2 cA = rA, cB = rB;
            if (jA + 2 < end)
                rA = *(const uint2*)&q[(size_t)ssend[jA + 2] * D + hl * 4];
            if (jB + 2 < end)
                rB = *(const uint2*)&q[(size_t)ssend[jB + 2] * D + hl * 4];
            step(cA, mA, lA, cA0, cA1, cA2, cA3);
            step(cB, mB, lB, cB0, cB1, cB2, cB3);
        }
        if (jA < end)
            step(rA, mA, lA, cA0, cA1, cA2, cA3);

        // merge stream B into A (in-lane flash merge)
        {
            const float nm = fmaxf(mA, mB);
            const float s0 = __expf(mA - nm), s1 = __expf(mB - nm);
            lA  = lA  * s0 + lB  * s1;
            cA0 = cA0 * s0 + cB0 * s1;
            cA1 = cA1 * s0 + cB1 * s1;
            cA2 = cA2 * s0 + cB2 * s1;
            cA3 = cA3 * s0 + cB3 * s1;
            mA = nm;
        }

        const float inv = (lA > 0.f) ? (1.f / lA) : 0.f;
        float r0 = fmaxf(cA0 * inv, 0.f);
        float r1 = fmaxf(cA1 * inv, 0.f);
        float r2 = fmaxf(cA2 * inv, 0.f);
        float r3 = fmaxf(cA3 * inv, 0.f);

        // head-mean: lanes hl, hl^8, hl^16, hl^24 hold heads 0..3 of same f
        // (xor 8 and 16 stay within the 32-lane half)
        r0 += __shfl_xor(r0, 8);  r0 += __shfl_xor(r0, 16);
        r1 += __shfl_xor(r1, 8);  r1 += __shfl_xor(r1, 16);
        r2 += __shfl_xor(r2, 8);  r2 += __shfl_xor(r2, 16);
        r3 += __shfl_xor(r3, 8);  r3 += __shfl_xor(r3, 16);
        if (hl < 8) {
            float4 o = {0.25f * r0, 0.25f * r1, 0.25f * r2, 0.25f * r3};
            *(float4*)&out[(size_t)n * NF + hl * 4] = o;
        }
    }
}

extern "C" void kernel_launch(void* const* d_in, const int* in_sizes, int n_in,
                              void* d_out, int out_size, void* d_ws, size_t ws_size,
                              hipStream_t stream)
{
    const float* nodes = (const float*)d_in[0];
    const float* W1    = (const float*)d_in[1];
    const float* b1    = (const float*)d_in[2];
    const float* g1    = (const float*)d_in[3];
    const float* be1   = (const float*)d_in[4];
    const float* W2    = (const float*)d_in[5];
    const float* b2    = (const float*)d_in[6];
    const float* g2    = (const float*)d_in[7];
    const float* be2   = (const float*)d_in[8];
    const int* senders   = (const int*)d_in[9];
    const int* receivers = (const int*)d_in[10];

    const int N = in_sizes[0] / D;
    const int E = in_sizes[9];
    float* out = (float*)d_out;

    char* ws = (char*)d_ws;
    unsigned short* qb = (unsigned short*)ws; ws += (size_t)N * D * 2;
    unsigned short* wt = (unsigned short*)ws; ws += 4 * 128 * 128 * 2;
    int* cnt      = (int*)ws;    ws += (size_t)N * 4;
    int* rowptr   = (int*)ws;    ws += (size_t)(N + 2) * 4;
    int* cursor   = (int*)ws;    ws += (size_t)N * 4;
    int* bsum     = (int*)ws;    ws += 256 * 4;
    int* ssend    = (int*)ws;    ws += (size_t)E * 4;

    const int zb = (N + 1023) / 1024;
    const int nwt32 = (N + 31) / 32;
    const int mlpBlocks = (nwt32 + 3) / 4;
    const int nb = (N + 1023) / 1024;

    // 1: weight split + counter zero
    prep_kernel<<<16 + zb, 256, 0, stream>>>(W1, W2, wt, cnt, N);

    // 2: 32-rows/wave MFMA MLP + edge histogram (tail blocks)
    mlp_hist_kernel<<<mlpBlocks + 128, 256, 0, stream>>>(
        nodes, wt, b1, g1, be1, b2, g2, be2, qb, N,
        receivers, cnt, E, mlpBlocks);

    // 3-5: CSR scan
    scan_blocks_kernel<<<nb, 256, 0, stream>>>(cnt, rowptr, bsum, N);
    scan_top_kernel<<<1, 256, 0, stream>>>(bsum, nb);
    scan_add_kernel<<<(N + 255) / 256, 256, 0, stream>>>(rowptr, cursor, bsum, N, E);

    // 6: bucket-fill receiver-sorted sender list
    fill_kernel<<<(E + 255) / 256, 256, 0, stream>>>(senders, receivers, cursor, ssend, E);

    // 7: one-node-per-half fused attention + epilogue
    node_attn_kernel<<<(N + 7) / 8, 256, 0, stream>>>(qb, rowptr, ssend, out, N);
}